// Round 1
// baseline (393.544 us; speedup 1.0000x reference)
//
#include <hip/hip_runtime.h>
#include <math.h>

#define IDIM 2048
#define NE   64
#define TOPK 8
#define NB   16384
#define TM   32      // rows per block
#define DK   32      // K-chunk
#define LST  36      // LDS row stride in floats (DK+4, keeps 16B alignment, breaks bank pow2)

__device__ __forceinline__ double softplus_d(double v) {
    return (v > 0.0) ? (v + log1p(exp(-v))) : log1p(exp(v));
}

__global__ void init_ws_kernel(float* ws) {
    int t = threadIdx.x;
    if (t < 2 * NE + 1) ws[t] = 0.0f;
}

// ws layout: [0..63] f counts, [64..127] p sums, [128] z sum
__global__ __launch_bounds__(256, 2) void gate_main_kernel(
    const float* __restrict__ x, const float* __restrict__ noise,
    const float* __restrict__ Wg, const float* __restrict__ bg,
    const float* __restrict__ Wn,
    float* __restrict__ out_w, float* __restrict__ out_i,
    float* __restrict__ ws)
{
    __shared__ float sX[TM][LST];
    __shared__ float sWg[NE][LST];
    __shared__ float sWn[NE][LST];
    __shared__ double sNoisy[TM][NE + 1];
    __shared__ double sLog[TM][NE + 1];
    __shared__ float sP[NE];
    __shared__ float sZ;

    const int t = threadIdx.x;
    const int row0 = blockIdx.x * TM;
    const int ex = t & 31;   // expert group: experts ex, ex+32
    const int ry = t >> 5;   // row group: rows ry + 8*i, i=0..3

    if (t < NE) sP[t] = 0.0f;
    if (t == 0) sZ = 0.0f;

    double accg[4][2];
    double accn[4][2];
    #pragma unroll
    for (int i = 0; i < 4; ++i)
        #pragma unroll
        for (int j = 0; j < 2; ++j) { accg[i][j] = 0.0; accn[i][j] = 0.0; }

    const int lrow = t >> 3;  // 0..31 (loader row)
    const int lc4  = t & 7;   // 0..7  (loader float4 col)

    for (int k0 = 0; k0 < IDIM; k0 += DK) {
        // stage x tile (32 x 32 f32): one float4 per thread
        {
            float4 v = *(const float4*)&x[(size_t)(row0 + lrow) * IDIM + k0 + lc4 * 4];
            *(float4*)&sX[lrow][lc4 * 4] = v;
        }
        // stage Wg/Wn tiles (64 x 32 each): two float4 per thread per matrix
        {
            float4 g0 = *(const float4*)&Wg[(size_t)lrow        * IDIM + k0 + lc4 * 4];
            float4 g1 = *(const float4*)&Wg[(size_t)(lrow + 32) * IDIM + k0 + lc4 * 4];
            float4 n0 = *(const float4*)&Wn[(size_t)lrow        * IDIM + k0 + lc4 * 4];
            float4 n1 = *(const float4*)&Wn[(size_t)(lrow + 32) * IDIM + k0 + lc4 * 4];
            *(float4*)&sWg[lrow][lc4 * 4]      = g0;
            *(float4*)&sWg[lrow + 32][lc4 * 4] = g1;
            *(float4*)&sWn[lrow][lc4 * 4]      = n0;
            *(float4*)&sWn[lrow + 32][lc4 * 4] = n1;
        }
        __syncthreads();

        #pragma unroll
        for (int kk = 0; kk < DK; kk += 4) {
            float4 xv[4], gv[2], nv[2];
            #pragma unroll
            for (int i = 0; i < 4; ++i) xv[i] = *(const float4*)&sX[ry + 8 * i][kk];
            #pragma unroll
            for (int j = 0; j < 2; ++j) {
                gv[j] = *(const float4*)&sWg[ex + 32 * j][kk];
                nv[j] = *(const float4*)&sWn[ex + 32 * j][kk];
            }
            #pragma unroll
            for (int q = 0; q < 4; ++q) {
                double xd[4], gd[2], nd[2];
                #pragma unroll
                for (int i = 0; i < 4; ++i) xd[i] = (double)((const float*)&xv[i])[q];
                #pragma unroll
                for (int j = 0; j < 2; ++j) {
                    gd[j] = (double)((const float*)&gv[j])[q];
                    nd[j] = (double)((const float*)&nv[j])[q];
                }
                #pragma unroll
                for (int i = 0; i < 4; ++i)
                    #pragma unroll
                    for (int j = 0; j < 2; ++j) {
                        accg[i][j] = fma(xd[i], gd[j], accg[i][j]);
                        accn[i][j] = fma(xd[i], nd[j], accn[i][j]);
                    }
            }
        }
        __syncthreads();
    }

    // epilogue: bias, softplus, noisy logits -> LDS row arrays (fp64)
    {
        float bgv0 = bg[ex];
        float bgv1 = bg[ex + 32];
        #pragma unroll
        for (int i = 0; i < 4; ++i) {
            int r = ry + 8 * i;
            int grow = row0 + r;
            #pragma unroll
            for (int j = 0; j < 2; ++j) {
                int e = ex + 32 * j;
                double lg = accg[i][j] + (double)(j == 0 ? bgv0 : bgv1);
                double sp = softplus_d(accn[i][j]);
                double nz = (double)noise[(size_t)grow * NE + e];
                sLog[r][e] = lg;
                sNoisy[r][e] = fma(nz, sp, lg);
            }
        }
    }
    __syncthreads();

    // per-row: top-8 (lowest-index tie-break), softmax, argmax, p, z
    if (t < TM) {
        const int r = t;
        const int grow = row0 + r;
        unsigned long long mask = 0ull;
        double tkv[TOPK];
        int tki[TOPK];
        #pragma unroll
        for (int k = 0; k < TOPK; ++k) {
            double best = -1e300;
            int bi = 0;
            for (int e = 0; e < NE; ++e) {
                if (mask & (1ull << e)) continue;
                double v = sNoisy[r][e];
                if (v > best) { best = v; bi = e; }
            }
            mask |= 1ull << bi;
            tkv[k] = best;
            tki[k] = bi;
        }
        // softmax over top-8 (tkv[0] is the max)
        double m0 = tkv[0];
        double ex_[TOPK];
        double s = 0.0;
        #pragma unroll
        for (int k = 0; k < TOPK; ++k) { ex_[k] = exp(tkv[k] - m0); s += ex_[k]; }
        double inv = 1.0 / s;
        #pragma unroll
        for (int k = 0; k < TOPK; ++k) {
            out_w[(size_t)grow * TOPK + k] = (float)(ex_[k] * inv);
            out_i[(size_t)grow * TOPK + k] = (float)tki[k];
        }
        // dispatch histogram (argmax == top-1 index)
        atomicAdd(&ws[tki[0]], 1.0f);
        // p = softmax(logits), z = logsumexp(logits)^2
        double lm = -1e300;
        for (int e = 0; e < NE; ++e) lm = fmax(lm, sLog[r][e]);
        double se = 0.0;
        for (int e = 0; e < NE; ++e) se += exp(sLog[r][e] - lm);
        double lse = lm + log(se);
        atomicAdd(&sZ, (float)(lse * lse));
        double invs = 1.0 / se;
        for (int e = 0; e < NE; ++e)
            atomicAdd(&sP[e], (float)(exp(sLog[r][e] - lm) * invs));
    }
    __syncthreads();
    if (t < NE) atomicAdd(&ws[NE + t], sP[t]);
    if (t == 0) atomicAdd(&ws[2 * NE], sZ);
}

__global__ void finalize_kernel(const float* __restrict__ ws, float* __restrict__ out) {
    int t = threadIdx.x; // 64 threads, one wave
    float v = (ws[t] / (float)NB) * (ws[NE + t] / (float)NB);
    #pragma unroll
    for (int o = 32; o > 0; o >>= 1) v += __shfl_down(v, o);
    if (t == 0) {
        out[2 * NB * TOPK]     = (float)NE * v;
        out[2 * NB * TOPK + 1] = ws[2 * NE] / (float)NB;
    }
}

extern "C" void kernel_launch(void* const* d_in, const int* in_sizes, int n_in,
                              void* d_out, int out_size, void* d_ws, size_t ws_size,
                              hipStream_t stream) {
    const float* x     = (const float*)d_in[0];
    const float* noise = (const float*)d_in[1];
    const float* Wg    = (const float*)d_in[2];
    const float* bg    = (const float*)d_in[3];
    const float* Wn    = (const float*)d_in[4];
    float* out = (float*)d_out;
    float* ws  = (float*)d_ws;

    hipLaunchKernelGGL(init_ws_kernel, dim3(1), dim3(256), 0, stream, ws);
    hipLaunchKernelGGL(gate_main_kernel, dim3(NB / TM), dim3(256), 0, stream,
                       x, noise, Wg, bg, Wn,
                       out, out + (size_t)NB * TOPK, ws);
    hipLaunchKernelGGL(finalize_kernel, dim3(1), dim3(64), 0, stream, ws, out);
}

// Round 2
// 262.920 us; speedup vs baseline: 1.4968x; 1.4968x over previous
//
#include <hip/hip_runtime.h>
#include <math.h>

#define IDIM 2048
#define NE   64
#define TOPK 8
#define NB   16384
#define TM   32      // rows per block
#define DK   32      // K-chunk per staging step
#define KH   1024    // K half per team
#define LSX  36      // LDS row stride (floats)

// LDS layout (bytes):
//   [0      .. 46080)  stage: 2 teams x (X[32][36] + Wg[64][36] + Wn[64][36]) floats
//   [0      .. 34816)  xfer alias: double[256][17]   (used after main loop only)
//   [46080  .. 62720)  sNoisy: double[32][65]
//   [62720  .. 71168)  sLogF:  float[32][66]
//   [71168  .. 71424)  sP[64]
//   [71424  .. 71680)  sF[64]
//   [71680  .. 71684)  sZ
#define SMEM_BYTES 71696

__device__ __forceinline__ double softplus_d(double v) {
    return (v > 0.0) ? (v + log1p(exp(-v))) : log1p(exp(v));
}

__global__ void init_ws_kernel(float* ws) {
    int t = threadIdx.x;
    if (t < 2 * NE + 1) ws[t] = 0.0f;
}

// ws layout: [0..63] f counts, [64..127] p sums, [128] z sum
__global__ __launch_bounds__(512, 4) void gate_main_kernel(
    const float* __restrict__ x, const float* __restrict__ noise,
    const float* __restrict__ Wg, const float* __restrict__ bg,
    const float* __restrict__ Wn,
    float* __restrict__ out_w, float* __restrict__ out_i,
    float* __restrict__ ws)
{
    __shared__ alignas(16) unsigned char smem[SMEM_BYTES];

    const int t    = threadIdx.x;
    const int team = t >> 8;        // 0 or 1 (K half)
    const int lt   = t & 255;
    const int ex   = lt & 31;       // expert col: experts ex, ex+32
    const int ry   = lt >> 5;       // row group: rows ry + 8*i
    const int row0 = blockIdx.x * TM;

    float* stg  = (float*)smem + team * 5760;
    float* sX   = stg;            // [32][36]
    float* sWg  = stg + 1152;     // [64][36]
    float* sWn  = stg + 3456;     // [64][36]
    double* xfer = (double*)smem;                   // [256][17]
    double* sNoisy = (double*)(smem + 46080);       // [32][65]
    float*  sLogF  = (float*) (smem + 62720);       // [32][66]
    float*  sP = (float*)(smem + 71168);
    float*  sF = (float*)(smem + 71424);
    float*  sZ = (float*)(smem + 71680);

    if (t < NE) { sP[t] = 0.0f; sF[t] = 0.0f; }
    if (t == 0) sZ[0] = 0.0f;

    double accg[4][2];
    double accn[4][2];
    #pragma unroll
    for (int i = 0; i < 4; ++i)
        #pragma unroll
        for (int j = 0; j < 2; ++j) { accg[i][j] = 0.0; accn[i][j] = 0.0; }

    const int lrow = lt >> 3;        // 0..31
    const int lc4  = (lt & 7) * 4;   // 0,4,..,28

    const float* xp   = x  + (size_t)(row0 + lrow) * IDIM + team * KH + lc4;
    const float* wgp0 = Wg + (size_t)lrow        * IDIM + team * KH + lc4;
    const float* wgp1 = Wg + (size_t)(lrow + 32) * IDIM + team * KH + lc4;
    const float* wnp0 = Wn + (size_t)lrow        * IDIM + team * KH + lc4;
    const float* wnp1 = Wn + (size_t)(lrow + 32) * IDIM + team * KH + lc4;

    for (int k0 = 0; k0 < KH; k0 += DK) {
        float4 xv_ = *(const float4*)(xp   + k0);
        float4 g0  = *(const float4*)(wgp0 + k0);
        float4 g1  = *(const float4*)(wgp1 + k0);
        float4 n0  = *(const float4*)(wnp0 + k0);
        float4 n1  = *(const float4*)(wnp1 + k0);
        *(float4*)&sX [lrow * LSX + lc4]        = xv_;
        *(float4*)&sWg[lrow * LSX + lc4]        = g0;
        *(float4*)&sWg[(lrow + 32) * LSX + lc4] = g1;
        *(float4*)&sWn[lrow * LSX + lc4]        = n0;
        *(float4*)&sWn[(lrow + 32) * LSX + lc4] = n1;
        __syncthreads();

        #pragma unroll
        for (int kk = 0; kk < DK; kk += 4) {
            float4 xv[4], gv[2], nv[2];
            #pragma unroll
            for (int i = 0; i < 4; ++i) xv[i] = *(const float4*)&sX[(ry + 8 * i) * LSX + kk];
            #pragma unroll
            for (int j = 0; j < 2; ++j) {
                gv[j] = *(const float4*)&sWg[(ex + 32 * j) * LSX + kk];
                nv[j] = *(const float4*)&sWn[(ex + 32 * j) * LSX + kk];
            }
            #pragma unroll
            for (int q = 0; q < 4; ++q) {
                double xd[4], gd[2], nd[2];
                #pragma unroll
                for (int i = 0; i < 4; ++i) xd[i] = (double)((const float*)&xv[i])[q];
                #pragma unroll
                for (int j = 0; j < 2; ++j) {
                    gd[j] = (double)((const float*)&gv[j])[q];
                    nd[j] = (double)((const float*)&nv[j])[q];
                }
                #pragma unroll
                for (int i = 0; i < 4; ++i)
                    #pragma unroll
                    for (int j = 0; j < 2; ++j) {
                        accg[i][j] = fma(xd[i], gd[j], accg[i][j]);
                        accn[i][j] = fma(xd[i], nd[j], accn[i][j]);
                    }
            }
        }
        __syncthreads();
    }

    // ---- combine K halves via aliased LDS (stage buffers dead now) ----
    if (team == 1) {
        #pragma unroll
        for (int i = 0; i < 4; ++i)
            #pragma unroll
            for (int j = 0; j < 2; ++j) {
                xfer[lt * 17 + (i * 2 + j)]     = accg[i][j];
                xfer[lt * 17 + 8 + (i * 2 + j)] = accn[i][j];
            }
    }
    __syncthreads();
    if (team == 0) {
        float bgv0 = bg[ex];
        float bgv1 = bg[ex + 32];
        #pragma unroll
        for (int i = 0; i < 4; ++i) {
            int r = ry + 8 * i;
            int grow = row0 + r;
            #pragma unroll
            for (int j = 0; j < 2; ++j) {
                int e = ex + 32 * j;
                double g = accg[i][j] + xfer[lt * 17 + (i * 2 + j)];
                double n = accn[i][j] + xfer[lt * 17 + 8 + (i * 2 + j)];
                double lg = g + (double)(j == 0 ? bgv0 : bgv1);
                double sp = softplus_d(n);
                double nz = (double)noise[(size_t)grow * NE + e];
                sNoisy[r * 65 + e] = fma(nz, sp, lg);
                sLogF[r * 66 + e]  = (float)lg;
            }
        }
    }
    __syncthreads();

    // ---- wave-parallel epilogue: 8 waves x 4 rows, lane = expert ----
    const int wv   = t >> 6;
    const int lane = t & 63;
    float pacc = 0.0f;
    float zacc = 0.0f;

    #pragma unroll
    for (int rr = 0; rr < 4; ++rr) {
        const int r = wv * 4 + rr;
        const int grow = row0 + r;
        double vcur = sNoisy[r * 65 + lane];
        float  lg   = sLogF[r * 66 + lane];

        double tkv[TOPK];
        int    tki[TOPK];
        #pragma unroll
        for (int k = 0; k < TOPK; ++k) {
            double mv = vcur;
            int    mi = lane;
            #pragma unroll
            for (int o = 32; o > 0; o >>= 1) {
                double ov = __shfl_xor(mv, o);
                int    oi = __shfl_xor(mi, o);
                if (ov > mv || (ov == mv && oi < mi)) { mv = ov; mi = oi; }
            }
            tkv[k] = mv;
            tki[k] = mi;
            if (lane == mi) vcur = -1e300;
        }

        // softmax over top-8 (tkv[0] is the max), computed redundantly per lane
        double m0 = tkv[0];
        double w[TOPK];
        double s = 0.0;
        #pragma unroll
        for (int k = 0; k < TOPK; ++k) { w[k] = exp(tkv[k] - m0); s += w[k]; }
        double inv = 1.0 / s;
        float myw = 0.0f; int myi = 0;
        #pragma unroll
        for (int k = 0; k < TOPK; ++k) {
            if (lane == k) { myw = (float)(w[k] * inv); myi = tki[k]; }
        }
        if (lane < TOPK) {
            out_w[(size_t)grow * TOPK + lane] = myw;
            out_i[(size_t)grow * TOPK + lane] = (float)myi;
        }
        if (lane == 0) atomicAdd(&sF[tki[0]], 1.0f);

        // p = softmax(logits) contribution, z = lse^2
        float rm = lg;
        #pragma unroll
        for (int o = 32; o > 0; o >>= 1) rm = fmaxf(rm, __shfl_xor(rm, o));
        float pe = expf(lg - rm);
        float ssum = pe;
        #pragma unroll
        for (int o = 32; o > 0; o >>= 1) ssum += __shfl_xor(ssum, o);
        pacc += pe / ssum;
        if (lane == 0) {
            float lse = rm + logf(ssum);
            zacc += lse * lse;
        }
    }

    atomicAdd(&sP[lane], pacc);
    if (lane == 0) atomicAdd(sZ, zacc);
    __syncthreads();

    if (t < NE) {
        atomicAdd(&ws[t],      sF[t]);
        atomicAdd(&ws[NE + t], sP[t]);
    }
    if (t == 0) atomicAdd(&ws[2 * NE], sZ[0]);
}

__global__ void finalize_kernel(const float* __restrict__ ws, float* __restrict__ out) {
    int t = threadIdx.x; // 64 threads, one wave
    float v = (ws[t] / (float)NB) * (ws[NE + t] / (float)NB);
    #pragma unroll
    for (int o = 32; o > 0; o >>= 1) v += __shfl_down(v, o);
    if (t == 0) {
        out[2 * NB * TOPK]     = (float)NE * v;
        out[2 * NB * TOPK + 1] = ws[2 * NE] / (float)NB;
    }
}

extern "C" void kernel_launch(void* const* d_in, const int* in_sizes, int n_in,
                              void* d_out, int out_size, void* d_ws, size_t ws_size,
                              hipStream_t stream) {
    const float* x     = (const float*)d_in[0];
    const float* noise = (const float*)d_in[1];
    const float* Wg    = (const float*)d_in[2];
    const float* bg    = (const float*)d_in[3];
    const float* Wn    = (const float*)d_in[4];
    float* out = (float*)d_out;
    float* ws  = (float*)d_ws;

    hipLaunchKernelGGL(init_ws_kernel, dim3(1), dim3(256), 0, stream, ws);
    hipLaunchKernelGGL(gate_main_kernel, dim3(NB / TM), dim3(512), 0, stream,
                       x, noise, Wg, bg, Wn,
                       out, out + (size_t)NB * TOPK, ws);
    hipLaunchKernelGGL(finalize_kernel, dim3(1), dim3(64), 0, stream, ws, out);
}